// Round 1
// baseline (374.575 us; speedup 1.0000x reference)
//
#include <hip/hip_runtime.h>
#include <cstdint>
#include <cstddef>

// Fixed problem constants (from reference setup)
#define B_    2
#define NQ_   21760
#define NK_   21760
#define D_    256
#define NH_   8
#define NL_   4
#define NP_   4
#define HD_   32
#define M_    (B_ * NQ_)   // 43520 = 340 * 128

typedef _Float16 f16x8 __attribute__((ext_vector_type(8)));
typedef _Float16 f16x4 __attribute__((ext_vector_type(4)));
typedef float    f32x4 __attribute__((ext_vector_type(4)));

// async global->LDS, 16B per lane; LDS dest = wave-uniform base + lane*16 [m97/m104]
__device__ __forceinline__ void lds16(const _Float16* g, _Float16* l) {
    __builtin_amdgcn_global_load_lds((const __attribute__((address_space(1))) void*)g,
                                     (__attribute__((address_space(3))) void*)l,
                                     16, 0, 0);
}

// ---------------------------------------------------------------------------
// Weight prep (all 4 in one launch): W[K][N] fp32 -> Bt[N][256] f16 transposed
// ---------------------------------------------------------------------------
__global__ __launch_bounds__(256) void wconv_all(const float* __restrict__ Wv,
                                                 const float* __restrict__ Woff,
                                                 const float* __restrict__ Wattn,
                                                 const float* __restrict__ Wout,
                                                 _Float16* __restrict__ Bv_t,
                                                 _Float16* __restrict__ Boff_t,
                                                 _Float16* __restrict__ Battn_t,
                                                 _Float16* __restrict__ Bout_t) {
    int id = blockIdx.x * 256 + threadIdx.x;
    if (id < 65536) {
        int k = id >> 8, n = id & 255;
        Bv_t[n * 256 + k] = (_Float16)Wv[k * 256 + n];
    } else if (id < 131072) {
        int e = id - 65536, k = e >> 8, n = e & 255;
        Boff_t[n * 256 + k] = (_Float16)Woff[k * 256 + n];
    } else if (id < 163840) {
        int e = id - 131072, k = e >> 7, n = e & 127;
        Battn_t[n * 256 + k] = (_Float16)Wattn[k * 128 + n];
    } else if (id < 229376) {
        int e = id - 163840, k = e >> 8, n = e & 255;
        Bout_t[n * 256 + k] = (_Float16)Wout[k * 256 + n];
    }
}

// ---------------------------------------------------------------------------
// fp32 -> f16 row conversion (one float4 -> one f16x4 per thread)
// Fused: converts flat (first n4each) then query (next n4each) in one launch.
// ---------------------------------------------------------------------------
__global__ __launch_bounds__(256) void aconv2(const float* __restrict__ X0,
                                              const float* __restrict__ X1,
                                              _Float16* __restrict__ Y0,
                                              _Float16* __restrict__ Y1, int n4each) {
    int id = blockIdx.x * 256 + threadIdx.x;
    const float* X;
    _Float16* Y;
    int e;
    if (id < n4each) { X = X0; Y = Y0; e = id; }
    else             { X = X1; Y = Y1; e = id - n4each; }
    float4 v = ((const float4*)X)[e];
    f16x4 o = {(_Float16)v.x, (_Float16)v.y, (_Float16)v.z, (_Float16)v.w};
    ((f16x4*)Y)[e] = o;
}

// ---------------------------------------------------------------------------
// f16 MFMA GEMM, m97-style: C[M,N] = A[M,256] @ Bt^T + bias
//   A: [M][256] f16 row-major; Bt: [N][256] f16 (pre-transposed weights)
// Tile 128x128, 256 thr = 4 waves (2x2), 4x4 frags 16x16x32, BK=32.
// Staging: global_load_lds width-16, XOR-swizzled 16B chunks:
//   LDS row r (32 f16 = 4 chunks); lds chunk q holds global chunk q ^ ((r>>1)&3)
//   -> fragment ds_read_b128 has max 2-way bank aliasing (free, m136).
// EPI: 0 = fp32 store, 1 = loc epilogue fp32, 2 = f16 store (value)
// ---------------------------------------------------------------------------
template <int N, int EPI>
__global__ __launch_bounds__(256) void gemm_f16(const _Float16* __restrict__ A,
                                                const _Float16* __restrict__ Bt,
                                                const float* __restrict__ bias,
                                                void* __restrict__ Cv,
                                                const float* __restrict__ rp) {
    constexpr int K = 256;
    constexpr int BK = 32;
    __shared__ _Float16 As[128 * 32];  // 8 KB
    __shared__ _Float16 Bs[128 * 32];  // 8 KB

    const int tid  = threadIdx.x;
    const int wave = tid >> 6;
    const int lane = tid & 63;
    const int m0 = blockIdx.x * 128;
    const int n0 = blockIdx.y * 128;
    const int wm = (wave & 1) << 6;
    const int wn = (wave >> 1) << 6;
    const int lm = lane & 15;
    const int quad = lane >> 4;

    // staging: wave stages rows [wave*32, wave*32+32) of As and Bs, 2 insts each
    // lane covers row srow (inst1) / srow+16 (inst2), lds chunk (lane&3),
    // which must hold global chunk g = (lane&3) ^ ((srow>>1)&3)  (same for +16)
    const int srow = (wave << 5) + (lane >> 2);
    const int g    = (lane & 3) ^ ((lane >> 3) & 3);
    const _Float16* Ag = A  + (size_t)(m0 + srow) * K + (g << 3);
    const _Float16* Bg = Bt + (size_t)(n0 + srow) * K + (g << 3);
    _Float16* AsW = &As[(wave << 5) * 32];
    _Float16* BsW = &Bs[(wave << 5) * 32];

    // fragment read: row = w*+i*16+lm, logical chunk = quad,
    // stored at lds chunk quad ^ ((lm>>1)&3)   [(row>>1)&3 == (lm>>1)&3]
    const int aswz = (quad ^ ((lm >> 1) & 3)) << 3;

    f32x4 acc[4][4];
#pragma unroll
    for (int i = 0; i < 4; ++i)
#pragma unroll
        for (int j = 0; j < 4; ++j) acc[i][j] = (f32x4){0.f, 0.f, 0.f, 0.f};

    for (int k0 = 0; k0 < K; k0 += BK) {
        if (k0) __syncthreads();  // prev iteration's ds_reads done before overwrite
        lds16(Ag + k0,                 AsW);
        lds16(Ag + (size_t)16 * K + k0, AsW + 16 * 32);
        lds16(Bg + k0,                 BsW);
        lds16(Bg + (size_t)16 * K + k0, BsW + 16 * 32);
        __syncthreads();          // drains vmcnt(0): tiles resident

        f16x8 af[4], bf[4];
#pragma unroll
        for (int i = 0; i < 4; ++i)
            af[i] = *(const f16x8*)&As[(wm + i * 16 + lm) * 32 + aswz];
#pragma unroll
        for (int j = 0; j < 4; ++j)
            bf[j] = *(const f16x8*)&Bs[(wn + j * 16 + lm) * 32 + aswz];
#pragma unroll
        for (int i = 0; i < 4; ++i)
#pragma unroll
            for (int j = 0; j < 4; ++j)
                acc[i][j] = __builtin_amdgcn_mfma_f32_16x16x32_f16(af[i], bf[j], acc[i][j], 0, 0, 0);
    }

    // epilogue: C/D layout col=lane&15, row=quad*4+reg  [m89/m91 verified]
    float bcol[4];
#pragma unroll
    for (int j = 0; j < 4; ++j) bcol[j] = bias[n0 + wn + j * 16 + lm];
#pragma unroll
    for (int i = 0; i < 4; ++i)
#pragma unroll
        for (int j = 0; j < 4; ++j) {
            const int col = n0 + wn + j * 16 + lm;
#pragma unroll
            for (int r = 0; r < 4; ++r) {
                const int row = m0 + wm + i * 16 + quad * 4 + r;
                float val = acc[i][j][r] + bcol[j];
                if (EPI == 1) {
                    const int c = col & 1;
                    const int l = (col >> 3) & 3;
                    const float inv = 1.f / (float)(128 >> l);
                    val = rp[(size_t)row * 8 + l * 2 + c] + val * inv;
                }
                if (EPI == 2)
                    ((_Float16*)Cv)[(size_t)row * N + col] = (_Float16)val;
                else
                    ((float*)Cv)[(size_t)row * N + col] = val;
            }
        }
}

// ---------------------------------------------------------------------------
// Deformable sampling core, setup-hoisted tap-parallel layout.
// One 32-lane unit per (b,q,h).
// Setup: lane owns pairs p = lane, lane+32 (p = sample*4 + tap); computes
//   weight (incl. attn) + flat element offset for its pairs ONCE.
// Main loop (16 iters): lane = tap(lane>>3) x chan-group(lane&7):
//   2 shfl broadcasts + one f16x4 (8B) gather + 4 FMA. Tap-reduce at end.
// value is f16 [B][NK][256]; writes core f16 [M][256].
// ---------------------------------------------------------------------------
__global__ __launch_bounds__(256) void deform_core(const _Float16* __restrict__ value,
                                                   const float* __restrict__ loc,
                                                   float* __restrict__ attn,
                                                   _Float16* __restrict__ core) {
    const int tid  = threadIdx.x;
    const int lane = tid & 31;
    const int u    = blockIdx.x * 8 + (tid >> 5);  // (b,q,h), h fastest
    const int h    = u & 7;
    const int bq   = u >> 3;
    const int b    = (bq >= NQ_) ? 1 : 0;

    const float myloc = loc[(size_t)u * 32 + lane];  // (l,p,c) 32 floats

    // softmax over 16 logits, in-place on attn output
    float lg = -1e30f;
    if (lane < 16) lg = attn[(size_t)u * 16 + lane];
    float m = lg;
#pragma unroll
    for (int mk = 8; mk; mk >>= 1) m = fmaxf(m, __shfl_xor(m, mk, 32));
    const float e = __expf(lg - m);
    float s = e;
#pragma unroll
    for (int mk = 8; mk; mk >>= 1) s += __shfl_xor(s, mk, 32);
    const float a = e / s;
    if (lane < 16) attn[(size_t)u * 16 + lane] = a;

    // ---- setup: per-(sample,tap) weight + offset, 2 pairs per lane ----
    int   off[2];
    float w[2];
#pragma unroll
    for (int t2 = 0; t2 < 2; ++t2) {
        const int p  = lane + (t2 << 5);   // pair id 0..63
        const int j  = p >> 2;             // sample 0..15 (l = j>>2, pt = j&3)
        const int dx = p & 1;
        const int dy = (p >> 1) & 1;
        const int l  = j >> 2;
        const int Wl = 128 >> l;
        const int st = (int)((0x15141000u >> (l << 3)) & 0xFFu) << 10;  // level starts
        const float aw = __shfl(a, j, 32);
        const float xr = __shfl(myloc, 2 * j, 32);
        const float yr = __shfl(myloc, 2 * j + 1, 32);
        const float x = xr * (float)Wl - 0.5f;
        const float y = yr * (float)Wl - 0.5f;
        const float x0f = floorf(x), y0f = floorf(y);
        const float fx = x - x0f, fy = y - y0f;
        const int xi = (int)x0f + dx;
        const int yi = (int)y0f + dy;
        const float wx = dx ? fx : 1.f - fx;
        const float wy = dy ? fy : 1.f - fy;
        const bool valid = (xi >= 0) && (xi < Wl) && (yi >= 0) && (yi < Wl);
        w[t2] = valid ? wx * wy * aw : 0.f;
        const int cx = min(max(xi, 0), Wl - 1);
        const int cy = min(max(yi, 0), Wl - 1);
        off[t2] = st + cy * Wl + cx;
    }

    // ---- main loop ----
    const int t = lane >> 3;               // my tap
    const _Float16* vb = value + (size_t)b * NK_ * D_ + h * HD_ + ((lane & 7) << 2);
    float4 acc = {0.f, 0.f, 0.f, 0.f};
#pragma unroll
    for (int j = 0; j < 8; ++j) {          // pairs 4j+t in slot 0
        const int src = (j << 2) + t;
        const float ww = __shfl(w[0], src, 32);
        const int   oo = __shfl(off[0], src, 32);
        const f16x4 v = *(const f16x4*)(vb + (size_t)oo * 256);
        acc.x += ww * (float)v[0];
        acc.y += ww * (float)v[1];
        acc.z += ww * (float)v[2];
        acc.w += ww * (float)v[3];
    }
#pragma unroll
    for (int j = 0; j < 8; ++j) {          // pairs 4(j+8)+t -> slot 1, src = 4j+t
        const int src = (j << 2) + t;
        const float ww = __shfl(w[1], src, 32);
        const int   oo = __shfl(off[1], src, 32);
        const f16x4 v = *(const f16x4*)(vb + (size_t)oo * 256);
        acc.x += ww * (float)v[0];
        acc.y += ww * (float)v[1];
        acc.z += ww * (float)v[2];
        acc.w += ww * (float)v[3];
    }

    // tap reduction: lanes {c, c+8, c+16, c+24} share a channel group
#pragma unroll
    for (int mk = 8; mk <= 16; mk <<= 1) {
        acc.x += __shfl_xor(acc.x, mk, 32);
        acc.y += __shfl_xor(acc.y, mk, 32);
        acc.z += __shfl_xor(acc.z, mk, 32);
        acc.w += __shfl_xor(acc.w, mk, 32);
    }
    if (lane < 8) {
        f16x4 o = {(_Float16)acc.x, (_Float16)acc.y, (_Float16)acc.z, (_Float16)acc.w};
        *(f16x4*)&core[(size_t)bq * 256 + h * 32 + ((lane & 7) << 2)] = o;
    }
}

// ---------------------------------------------------------------------------
extern "C" void kernel_launch(void* const* d_in, const int* in_sizes, int n_in,
                              void* d_out, int out_size, void* d_ws, size_t ws_size,
                              hipStream_t stream) {
    const float* query = (const float*)d_in[0];
    const float* rp    = (const float*)d_in[1];
    const float* flat  = (const float*)d_in[2];
    const float* Wv    = (const float*)d_in[5];
    const float* bv    = (const float*)d_in[6];
    const float* Woff  = (const float*)d_in[7];
    const float* boff  = (const float*)d_in[8];
    const float* Wattn = (const float*)d_in[9];
    const float* battn = (const float*)d_in[10];
    const float* Wout  = (const float*)d_in[11];
    const float* bout  = (const float*)d_in[12];

    float* out      = (float*)d_out;                 // (B,NQ,D)
    float* out_loc  = out + (size_t)M_ * D_;         // (B,NQ,NH,NL,NP,2)
    float* out_attn = out_loc + (size_t)M_ * D_;     // (B,NQ,NH,NL,NP)

    // ws: f16 weights + f16 activations
    _Float16* Bv_t    = (_Float16*)d_ws;             // [256][256]
    _Float16* Boff_t  = Bv_t + 65536;                // [256][256]
    _Float16* Battn_t = Boff_t + 65536;              // [128][256]
    _Float16* Bout_t  = Battn_t + 32768;             // [256][256]
    _Float16* flat16  = Bout_t + 65536;              // [M][256]
    _Float16* query16 = flat16 + (size_t)M_ * 256;   // [M][256]
    _Float16* value16 = query16 + (size_t)M_ * 256;  // [M][256]
    _Float16* core16  = value16 + (size_t)M_ * 256;  // [M][256]

    dim3 blk(256);
    // 0. weight prep (one launch)
    wconv_all<<<dim3(896), blk, 0, stream>>>(Wv, Woff, Wattn, Wout,
                                             Bv_t, Boff_t, Battn_t, Bout_t);
    // 0b. activation f16 conversion (flat + query fused into one launch)
    aconv2<<<dim3(2 * M_ * 64 / 256), blk, 0, stream>>>(flat, query, flat16, query16, M_ * 64);

    // 1. value16 = f16(flat @ Wv + bv)
    gemm_f16<256, 2><<<dim3(M_ / 128, 2), blk, 0, stream>>>(flat16, Bv_t, bv, value16, nullptr);
    // 2. loc = rp + (query @ Woff + boff)/norm  (direct to output)
    gemm_f16<256, 1><<<dim3(M_ / 128, 2), blk, 0, stream>>>(query16, Boff_t, boff, out_loc, rp);
    // 3. attn logits (direct to attn output; softmaxed in-place by deform_core)
    gemm_f16<128, 0><<<dim3(M_ / 128, 1), blk, 0, stream>>>(query16, Battn_t, battn, out_attn, nullptr);
    // 4. softmax + deformable sampling -> core16
    deform_core<<<dim3(M_ * NH_ / 8), blk, 0, stream>>>(value16, out_loc, out_attn, core16);
    // 5. out = core @ Wout + bout
    gemm_f16<256, 0><<<dim3(M_ / 128, 2), blk, 0, stream>>>(core16, Bout_t, bout, out, nullptr);
}

// Round 2
// 365.245 us; speedup vs baseline: 1.0255x; 1.0255x over previous
//
#include <hip/hip_runtime.h>
#include <cstdint>
#include <cstddef>

// Fixed problem constants (from reference setup)
#define B_    2
#define NQ_   21760
#define NK_   21760
#define D_    256
#define NH_   8
#define NL_   4
#define NP_   4
#define HD_   32
#define M_    (B_ * NQ_)   // 43520 = 340 * 128

typedef _Float16 f16x8 __attribute__((ext_vector_type(8)));
typedef _Float16 f16x4 __attribute__((ext_vector_type(4)));
typedef float    f32x4 __attribute__((ext_vector_type(4)));

// async global->LDS, 16B per lane; LDS dest = wave-uniform base + lane*16 [m97/m104]
__device__ __forceinline__ void lds16(const _Float16* g, _Float16* l) {
    __builtin_amdgcn_global_load_lds((const __attribute__((address_space(1))) void*)g,
                                     (__attribute__((address_space(3))) void*)l,
                                     16, 0, 0);
}

// ---------------------------------------------------------------------------
// Weight prep (all 4 in one launch): W[K][N] fp32 -> Bt[N][256] f16 transposed
// ---------------------------------------------------------------------------
__global__ __launch_bounds__(256) void wconv_all(const float* __restrict__ Wv,
                                                 const float* __restrict__ Woff,
                                                 const float* __restrict__ Wattn,
                                                 const float* __restrict__ Wout,
                                                 _Float16* __restrict__ Bv_t,
                                                 _Float16* __restrict__ Boff_t,
                                                 _Float16* __restrict__ Battn_t,
                                                 _Float16* __restrict__ Bout_t) {
    int id = blockIdx.x * 256 + threadIdx.x;
    if (id < 65536) {
        int k = id >> 8, n = id & 255;
        Bv_t[n * 256 + k] = (_Float16)Wv[k * 256 + n];
    } else if (id < 131072) {
        int e = id - 65536, k = e >> 8, n = e & 255;
        Boff_t[n * 256 + k] = (_Float16)Woff[k * 256 + n];
    } else if (id < 163840) {
        int e = id - 131072, k = e >> 7, n = e & 127;
        Battn_t[n * 256 + k] = (_Float16)Wattn[k * 128 + n];
    } else if (id < 229376) {
        int e = id - 163840, k = e >> 8, n = e & 255;
        Bout_t[n * 256 + k] = (_Float16)Wout[k * 256 + n];
    }
}

// ---------------------------------------------------------------------------
// fp32 -> f16 row conversion (one float4 -> one f16x4 per thread)
// Fused: converts flat (first n4each) then query (next n4each) in one launch.
// ---------------------------------------------------------------------------
__global__ __launch_bounds__(256) void aconv2(const float* __restrict__ X0,
                                              const float* __restrict__ X1,
                                              _Float16* __restrict__ Y0,
                                              _Float16* __restrict__ Y1, int n4each) {
    int id = blockIdx.x * 256 + threadIdx.x;
    const float* X;
    _Float16* Y;
    int e;
    if (id < n4each) { X = X0; Y = Y0; e = id; }
    else             { X = X1; Y = Y1; e = id - n4each; }
    float4 v = ((const float4*)X)[e];
    f16x4 o = {(_Float16)v.x, (_Float16)v.y, (_Float16)v.z, (_Float16)v.w};
    ((f16x4*)Y)[e] = o;
}

// ---------------------------------------------------------------------------
// f16 MFMA GEMM, m97-style: C[M,N] = A[M,256] @ Bt^T + bias
//   A: [M][256] f16 row-major; Bt: [N][256] f16 (pre-transposed weights)
// Tile 128x128, 256 thr = 4 waves (2x2), 4x4 frags 16x16x32, BK=32.
// Staging: global_load_lds width-16, XOR-swizzled 16B chunks:
//   LDS row r (32 f16 = 4 chunks); lds chunk q holds global chunk q ^ ((r>>1)&3)
//   -> fragment ds_read_b128 has max 2-way bank aliasing (free, m136).
// EPI: 0 = fp32 store, 1 = loc epilogue fp32, 2 = f16 store (value)
// ---------------------------------------------------------------------------
template <int N, int EPI>
__global__ __launch_bounds__(256) void gemm_f16(const _Float16* __restrict__ A,
                                                const _Float16* __restrict__ Bt,
                                                const float* __restrict__ bias,
                                                void* __restrict__ Cv,
                                                const float* __restrict__ rp) {
    constexpr int K = 256;
    constexpr int BK = 32;
    __shared__ _Float16 As[128 * 32];  // 8 KB
    __shared__ _Float16 Bs[128 * 32];  // 8 KB

    const int tid  = threadIdx.x;
    const int wave = tid >> 6;
    const int lane = tid & 63;
    const int m0 = blockIdx.x * 128;
    const int n0 = blockIdx.y * 128;
    const int wm = (wave & 1) << 6;
    const int wn = (wave >> 1) << 6;
    const int lm = lane & 15;
    const int quad = lane >> 4;

    // staging: wave stages rows [wave*32, wave*32+32) of As and Bs, 2 insts each
    // lane covers row srow (inst1) / srow+16 (inst2), lds chunk (lane&3),
    // which must hold global chunk g = (lane&3) ^ ((srow>>1)&3)  (same for +16)
    const int srow = (wave << 5) + (lane >> 2);
    const int g    = (lane & 3) ^ ((lane >> 3) & 3);
    const _Float16* Ag = A  + (size_t)(m0 + srow) * K + (g << 3);
    const _Float16* Bg = Bt + (size_t)(n0 + srow) * K + (g << 3);
    _Float16* AsW = &As[(wave << 5) * 32];
    _Float16* BsW = &Bs[(wave << 5) * 32];

    // fragment read: row = w*+i*16+lm, logical chunk = quad,
    // stored at lds chunk quad ^ ((lm>>1)&3)   [(row>>1)&3 == (lm>>1)&3]
    const int aswz = (quad ^ ((lm >> 1) & 3)) << 3;

    f32x4 acc[4][4];
#pragma unroll
    for (int i = 0; i < 4; ++i)
#pragma unroll
        for (int j = 0; j < 4; ++j) acc[i][j] = (f32x4){0.f, 0.f, 0.f, 0.f};

    for (int k0 = 0; k0 < K; k0 += BK) {
        if (k0) __syncthreads();  // prev iteration's ds_reads done before overwrite
        lds16(Ag + k0,                 AsW);
        lds16(Ag + (size_t)16 * K + k0, AsW + 16 * 32);
        lds16(Bg + k0,                 BsW);
        lds16(Bg + (size_t)16 * K + k0, BsW + 16 * 32);
        __syncthreads();          // drains vmcnt(0): tiles resident

        f16x8 af[4], bf[4];
#pragma unroll
        for (int i = 0; i < 4; ++i)
            af[i] = *(const f16x8*)&As[(wm + i * 16 + lm) * 32 + aswz];
#pragma unroll
        for (int j = 0; j < 4; ++j)
            bf[j] = *(const f16x8*)&Bs[(wn + j * 16 + lm) * 32 + aswz];
#pragma unroll
        for (int i = 0; i < 4; ++i)
#pragma unroll
            for (int j = 0; j < 4; ++j)
                acc[i][j] = __builtin_amdgcn_mfma_f32_16x16x32_f16(af[i], bf[j], acc[i][j], 0, 0, 0);
    }

    // epilogue: C/D layout col=lane&15, row=quad*4+reg  [m89/m91 verified]
    float bcol[4];
#pragma unroll
    for (int j = 0; j < 4; ++j) bcol[j] = bias[n0 + wn + j * 16 + lm];
#pragma unroll
    for (int i = 0; i < 4; ++i)
#pragma unroll
        for (int j = 0; j < 4; ++j) {
            const int col = n0 + wn + j * 16 + lm;
#pragma unroll
            for (int r = 0; r < 4; ++r) {
                const int row = m0 + wm + i * 16 + quad * 4 + r;
                float val = acc[i][j][r] + bcol[j];
                if (EPI == 1) {
                    const int c = col & 1;
                    const int l = (col >> 3) & 3;
                    const float inv = 1.f / (float)(128 >> l);
                    val = rp[(size_t)row * 8 + l * 2 + c] + val * inv;
                }
                if (EPI == 2)
                    ((_Float16*)Cv)[(size_t)row * N + col] = (_Float16)val;
                else
                    ((float*)Cv)[(size_t)row * N + col] = val;
            }
        }
}

// ---------------------------------------------------------------------------
// Deformable sampling core, setup-hoisted, 16B-gather layout.
// One 32-lane unit per (b,q,h).
// Setup: lane owns pairs p = lane, lane+32 (p = sample*4 + tap); computes
//   weight (incl. attn) + flat element offset for its pairs ONCE.
// Main loop (8 iters, was 16): lane = pair-slot (lane>>2) x chan-group (lane&3):
//   2 shfl broadcasts + ONE f16x8 (16B) gather + 8 FMA into f32 acc[8].
//   -> 256 gathers/unit instead of 512 (gather-address-throughput bound, R1).
// Tap/pair reduce: xor 4/8/16 over 8 floats; lanes 0..3 write f16x8 each.
// value is f16 [B][NK][256]; writes core f16 [M][256].
// ---------------------------------------------------------------------------
__global__ __launch_bounds__(256) void deform_core(const _Float16* __restrict__ value,
                                                   const float* __restrict__ loc,
                                                   float* __restrict__ attn,
                                                   _Float16* __restrict__ core) {
    const int tid  = threadIdx.x;
    const int lane = tid & 31;
    const int u    = blockIdx.x * 8 + (tid >> 5);  // (b,q,h), h fastest
    const int h    = u & 7;
    const int bq   = u >> 3;
    const int b    = (bq >= NQ_) ? 1 : 0;

    const float myloc = loc[(size_t)u * 32 + lane];  // (l,p,c) 32 floats

    // softmax over 16 logits, in-place on attn output
    float lg = -1e30f;
    if (lane < 16) lg = attn[(size_t)u * 16 + lane];
    float m = lg;
#pragma unroll
    for (int mk = 8; mk; mk >>= 1) m = fmaxf(m, __shfl_xor(m, mk, 32));
    const float e = __expf(lg - m);
    float s = e;
#pragma unroll
    for (int mk = 8; mk; mk >>= 1) s += __shfl_xor(s, mk, 32);
    const float a = e / s;
    if (lane < 16) attn[(size_t)u * 16 + lane] = a;

    // ---- setup: per-(sample,tap) weight + offset, 2 pairs per lane ----
    int   off[2];
    float w[2];
#pragma unroll
    for (int t2 = 0; t2 < 2; ++t2) {
        const int p  = lane + (t2 << 5);   // pair id 0..63
        const int j  = p >> 2;             // sample 0..15 (l = j>>2, pt = j&3)
        const int dx = p & 1;
        const int dy = (p >> 1) & 1;
        const int l  = j >> 2;
        const int Wl = 128 >> l;
        const int st = (int)((0x15141000u >> (l << 3)) & 0xFFu) << 10;  // level starts
        const float aw = __shfl(a, j, 32);
        const float xr = __shfl(myloc, 2 * j, 32);
        const float yr = __shfl(myloc, 2 * j + 1, 32);
        const float x = xr * (float)Wl - 0.5f;
        const float y = yr * (float)Wl - 0.5f;
        const float x0f = floorf(x), y0f = floorf(y);
        const float fx = x - x0f, fy = y - y0f;
        const int xi = (int)x0f + dx;
        const int yi = (int)y0f + dy;
        const float wx = dx ? fx : 1.f - fx;
        const float wy = dy ? fy : 1.f - fy;
        const bool valid = (xi >= 0) && (xi < Wl) && (yi >= 0) && (yi < Wl);
        w[t2] = valid ? wx * wy * aw : 0.f;
        const int cx = min(max(xi, 0), Wl - 1);
        const int cy = min(max(yi, 0), Wl - 1);
        off[t2] = st + cy * Wl + cx;
    }

    // ---- main loop: iter j processes pairs j*8 + (lane>>2), 16B per lane ----
    // pair p = j*8 + (lane>>2); slot = j>>2; src lane = p & 31 = ((j&3)<<3)+(lane>>2)
    const _Float16* vb = value + (size_t)b * NK_ * D_ + h * HD_ + ((lane & 3) << 3);
    float acc[8] = {0.f, 0.f, 0.f, 0.f, 0.f, 0.f, 0.f, 0.f};
#pragma unroll
    for (int j = 0; j < 8; ++j) {
        const int src = ((j & 3) << 3) + (lane >> 2);
        const float ww = __shfl(w[j >> 2], src, 32);
        const int   oo = __shfl(off[j >> 2], src, 32);
        const f16x8 v = *(const f16x8*)(vb + (size_t)oo * 256);
#pragma unroll
        for (int c = 0; c < 8; ++c) acc[c] += ww * (float)v[c];
    }

    // reduce over the 8 lanes sharing chan-group (lane&3): xor 4, 8, 16
#pragma unroll
    for (int mk = 4; mk <= 16; mk <<= 1)
#pragma unroll
        for (int c = 0; c < 8; ++c) acc[c] += __shfl_xor(acc[c], mk, 32);

    if (lane < 4) {
        f16x8 o;
#pragma unroll
        for (int c = 0; c < 8; ++c) o[c] = (_Float16)acc[c];
        *(f16x8*)&core[(size_t)bq * 256 + h * 32 + (lane << 3)] = o;
    }
}

// ---------------------------------------------------------------------------
extern "C" void kernel_launch(void* const* d_in, const int* in_sizes, int n_in,
                              void* d_out, int out_size, void* d_ws, size_t ws_size,
                              hipStream_t stream) {
    const float* query = (const float*)d_in[0];
    const float* rp    = (const float*)d_in[1];
    const float* flat  = (const float*)d_in[2];
    const float* Wv    = (const float*)d_in[5];
    const float* bv    = (const float*)d_in[6];
    const float* Woff  = (const float*)d_in[7];
    const float* boff  = (const float*)d_in[8];
    const float* Wattn = (const float*)d_in[9];
    const float* battn = (const float*)d_in[10];
    const float* Wout  = (const float*)d_in[11];
    const float* bout  = (const float*)d_in[12];

    float* out      = (float*)d_out;                 // (B,NQ,D)
    float* out_loc  = out + (size_t)M_ * D_;         // (B,NQ,NH,NL,NP,2)
    float* out_attn = out_loc + (size_t)M_ * D_;     // (B,NQ,NH,NL,NP)

    // ws: f16 weights + f16 activations
    _Float16* Bv_t    = (_Float16*)d_ws;             // [256][256]
    _Float16* Boff_t  = Bv_t + 65536;                // [256][256]
    _Float16* Battn_t = Boff_t + 65536;              // [128][256]
    _Float16* Bout_t  = Battn_t + 32768;             // [256][256]
    _Float16* flat16  = Bout_t + 65536;              // [M][256]
    _Float16* query16 = flat16 + (size_t)M_ * 256;   // [M][256]
    _Float16* value16 = query16 + (size_t)M_ * 256;  // [M][256]
    _Float16* core16  = value16 + (size_t)M_ * 256;  // [M][256]

    dim3 blk(256);
    // 0. weight prep (one launch)
    wconv_all<<<dim3(896), blk, 0, stream>>>(Wv, Woff, Wattn, Wout,
                                             Bv_t, Boff_t, Battn_t, Bout_t);
    // 0b. activation f16 conversion (flat + query fused into one launch)
    aconv2<<<dim3(2 * M_ * 64 / 256), blk, 0, stream>>>(flat, query, flat16, query16, M_ * 64);

    // 1. value16 = f16(flat @ Wv + bv)
    gemm_f16<256, 2><<<dim3(M_ / 128, 2), blk, 0, stream>>>(flat16, Bv_t, bv, value16, nullptr);
    // 2. loc = rp + (query @ Woff + boff)/norm  (direct to output)
    gemm_f16<256, 1><<<dim3(M_ / 128, 2), blk, 0, stream>>>(query16, Boff_t, boff, out_loc, rp);
    // 3. attn logits (direct to attn output; softmaxed in-place by deform_core)
    gemm_f16<128, 0><<<dim3(M_ / 128, 1), blk, 0, stream>>>(query16, Battn_t, battn, out_attn, nullptr);
    // 4. softmax + deformable sampling -> core16
    deform_core<<<dim3(M_ * NH_ / 8), blk, 0, stream>>>(value16, out_loc, out_attn, core16);
    // 5. out = core @ Wout + bout
    gemm_f16<256, 0><<<dim3(M_ / 128, 2), blk, 0, stream>>>(core16, Bout_t, bout, out, nullptr);
}

// Round 3
// 365.170 us; speedup vs baseline: 1.0258x; 1.0002x over previous
//
#include <hip/hip_runtime.h>
#include <cstdint>
#include <cstddef>

// Fixed problem constants (from reference setup)
#define B_    2
#define NQ_   21760
#define NK_   21760
#define D_    256
#define NH_   8
#define NL_   4
#define NP_   4
#define HD_   32
#define M_    (B_ * NQ_)   // 43520 = 340 * 128

typedef _Float16 f16x8 __attribute__((ext_vector_type(8)));
typedef _Float16 f16x4 __attribute__((ext_vector_type(4)));
typedef float    f32x4 __attribute__((ext_vector_type(4)));

// async global->LDS, 16B per lane; LDS dest = wave-uniform base + lane*16 [m97/m104]
__device__ __forceinline__ void lds16(const _Float16* g, _Float16* l) {
    __builtin_amdgcn_global_load_lds((const __attribute__((address_space(1))) void*)g,
                                     (__attribute__((address_space(3))) void*)l,
                                     16, 0, 0);
}

// ---------------------------------------------------------------------------
// Weight prep (all 4 in one launch): W[K][N] fp32 -> Bt[N][256] f16 transposed
// ---------------------------------------------------------------------------
__global__ __launch_bounds__(256) void wconv_all(const float* __restrict__ Wv,
                                                 const float* __restrict__ Woff,
                                                 const float* __restrict__ Wattn,
                                                 const float* __restrict__ Wout,
                                                 _Float16* __restrict__ Bv_t,
                                                 _Float16* __restrict__ Boff_t,
                                                 _Float16* __restrict__ Battn_t,
                                                 _Float16* __restrict__ Bout_t) {
    int id = blockIdx.x * 256 + threadIdx.x;
    if (id < 65536) {
        int k = id >> 8, n = id & 255;
        Bv_t[n * 256 + k] = (_Float16)Wv[k * 256 + n];
    } else if (id < 131072) {
        int e = id - 65536, k = e >> 8, n = e & 255;
        Boff_t[n * 256 + k] = (_Float16)Woff[k * 256 + n];
    } else if (id < 163840) {
        int e = id - 131072, k = e >> 7, n = e & 127;
        Battn_t[n * 256 + k] = (_Float16)Wattn[k * 128 + n];
    } else if (id < 229376) {
        int e = id - 163840, k = e >> 8, n = e & 255;
        Bout_t[n * 256 + k] = (_Float16)Wout[k * 256 + n];
    }
}

// ---------------------------------------------------------------------------
// fp32 -> f16 row conversion (one float4 -> one f16x4 per thread)
// Fused: converts flat (first n4each) then query (next n4each) in one launch.
// ---------------------------------------------------------------------------
__global__ __launch_bounds__(256) void aconv2(const float* __restrict__ X0,
                                              const float* __restrict__ X1,
                                              _Float16* __restrict__ Y0,
                                              _Float16* __restrict__ Y1, int n4each) {
    int id = blockIdx.x * 256 + threadIdx.x;
    const float* X;
    _Float16* Y;
    int e;
    if (id < n4each) { X = X0; Y = Y0; e = id; }
    else             { X = X1; Y = Y1; e = id - n4each; }
    float4 v = ((const float4*)X)[e];
    f16x4 o = {(_Float16)v.x, (_Float16)v.y, (_Float16)v.z, (_Float16)v.w};
    ((f16x4*)Y)[e] = o;
}

// ---------------------------------------------------------------------------
// f16 MFMA GEMM, m97-style: C[M,N] = A[M,256] @ Bt^T + bias
//   A: [M][256] f16 row-major; Bt: [N][256] f16 (pre-transposed weights)
// Tile 128x128, 256 thr = 4 waves (2x2), 4x4 frags 16x16x32, BK=32.
// Staging: global_load_lds width-16, XOR-swizzled 16B chunks:
//   LDS row r (32 f16 = 4 chunks); lds chunk q holds global chunk q ^ ((r>>1)&3)
//   -> fragment ds_read_b128 has max 2-way bank aliasing (free, m136).
// EPI: 0 = fp32 store, 1 = loc epilogue fp32, 2 = f16 store (value)
// ---------------------------------------------------------------------------
template <int N, int EPI>
__global__ __launch_bounds__(256) void gemm_f16(const _Float16* __restrict__ A,
                                                const _Float16* __restrict__ Bt,
                                                const float* __restrict__ bias,
                                                void* __restrict__ Cv,
                                                const float* __restrict__ rp) {
    constexpr int K = 256;
    constexpr int BK = 32;
    __shared__ _Float16 As[128 * 32];  // 8 KB
    __shared__ _Float16 Bs[128 * 32];  // 8 KB

    const int tid  = threadIdx.x;
    const int wave = tid >> 6;
    const int lane = tid & 63;
    const int m0 = blockIdx.x * 128;
    const int n0 = blockIdx.y * 128;
    const int wm = (wave & 1) << 6;
    const int wn = (wave >> 1) << 6;
    const int lm = lane & 15;
    const int quad = lane >> 4;

    // staging: wave stages rows [wave*32, wave*32+32) of As and Bs, 2 insts each
    // lane covers row srow (inst1) / srow+16 (inst2), lds chunk (lane&3),
    // which must hold global chunk g = (lane&3) ^ ((srow>>1)&3)  (same for +16)
    const int srow = (wave << 5) + (lane >> 2);
    const int g    = (lane & 3) ^ ((lane >> 3) & 3);
    const _Float16* Ag = A  + (size_t)(m0 + srow) * K + (g << 3);
    const _Float16* Bg = Bt + (size_t)(n0 + srow) * K + (g << 3);
    _Float16* AsW = &As[(wave << 5) * 32];
    _Float16* BsW = &Bs[(wave << 5) * 32];

    // fragment read: row = w*+i*16+lm, logical chunk = quad,
    // stored at lds chunk quad ^ ((lm>>1)&3)   [(row>>1)&3 == (lm>>1)&3]
    const int aswz = (quad ^ ((lm >> 1) & 3)) << 3;

    f32x4 acc[4][4];
#pragma unroll
    for (int i = 0; i < 4; ++i)
#pragma unroll
        for (int j = 0; j < 4; ++j) acc[i][j] = (f32x4){0.f, 0.f, 0.f, 0.f};

    for (int k0 = 0; k0 < K; k0 += BK) {
        if (k0) __syncthreads();  // prev iteration's ds_reads done before overwrite
        lds16(Ag + k0,                 AsW);
        lds16(Ag + (size_t)16 * K + k0, AsW + 16 * 32);
        lds16(Bg + k0,                 BsW);
        lds16(Bg + (size_t)16 * K + k0, BsW + 16 * 32);
        __syncthreads();          // drains vmcnt(0): tiles resident

        f16x8 af[4], bf[4];
#pragma unroll
        for (int i = 0; i < 4; ++i)
            af[i] = *(const f16x8*)&As[(wm + i * 16 + lm) * 32 + aswz];
#pragma unroll
        for (int j = 0; j < 4; ++j)
            bf[j] = *(const f16x8*)&Bs[(wn + j * 16 + lm) * 32 + aswz];
#pragma unroll
        for (int i = 0; i < 4; ++i)
#pragma unroll
            for (int j = 0; j < 4; ++j)
                acc[i][j] = __builtin_amdgcn_mfma_f32_16x16x32_f16(af[i], bf[j], acc[i][j], 0, 0, 0);
    }

    // epilogue: C/D layout col=lane&15, row=quad*4+reg  [m89/m91 verified]
    float bcol[4];
#pragma unroll
    for (int j = 0; j < 4; ++j) bcol[j] = bias[n0 + wn + j * 16 + lm];
#pragma unroll
    for (int i = 0; i < 4; ++i)
#pragma unroll
        for (int j = 0; j < 4; ++j) {
            const int col = n0 + wn + j * 16 + lm;
#pragma unroll
            for (int r = 0; r < 4; ++r) {
                const int row = m0 + wm + i * 16 + quad * 4 + r;
                float val = acc[i][j][r] + bcol[j];
                if (EPI == 1) {
                    const int c = col & 1;
                    const int l = (col >> 3) & 3;
                    const float inv = 1.f / (float)(128 >> l);
                    val = rp[(size_t)row * 8 + l * 2 + c] + val * inv;
                }
                if (EPI == 2)
                    ((_Float16*)Cv)[(size_t)row * N + col] = (_Float16)val;
                else
                    ((float*)Cv)[(size_t)row * N + col] = val;
            }
        }
}

// ---------------------------------------------------------------------------
// Deformable sampling core, setup-hoisted, 16B-gather, BATCHED-MLP layout.
// One 32-lane unit per (b,q,h).
// Setup: lane owns pairs p = lane, lane+32 (p = sample*4 + tap); computes
//   weight (incl. attn) + flat element offset for its pairs ONCE.
// Then 16 shfls redistribute to per-lane w8[8]/off8[8] (all pairs this lane
// will consume), OUT of the load loop.
// Main body: issue ALL 8 f16x8 (16B) gathers into vv[8] (forces ~8 loads in
// flight per lane; R2 theory: loop was concurrency-starved at VGPR=32 with
// per-iter shfl->load dependency), then 64 FMAs.
// Reduce: xor 4/8/16 over 8 floats; lanes 0..3 write f16x8 each.
// value is f16 [B][NK][256]; writes core f16 [M][256].
// ---------------------------------------------------------------------------
__global__ __launch_bounds__(256) void deform_core(const _Float16* __restrict__ value,
                                                   const float* __restrict__ loc,
                                                   float* __restrict__ attn,
                                                   _Float16* __restrict__ core) {
    const int tid  = threadIdx.x;
    const int lane = tid & 31;
    const int u    = blockIdx.x * 8 + (tid >> 5);  // (b,q,h), h fastest
    const int h    = u & 7;
    const int bq   = u >> 3;
    const int b    = (bq >= NQ_) ? 1 : 0;

    const float myloc = loc[(size_t)u * 32 + lane];  // (l,p,c) 32 floats

    // softmax over 16 logits, in-place on attn output
    float lg = -1e30f;
    if (lane < 16) lg = attn[(size_t)u * 16 + lane];
    float m = lg;
#pragma unroll
    for (int mk = 8; mk; mk >>= 1) m = fmaxf(m, __shfl_xor(m, mk, 32));
    const float e = __expf(lg - m);
    float s = e;
#pragma unroll
    for (int mk = 8; mk; mk >>= 1) s += __shfl_xor(s, mk, 32);
    const float a = e / s;
    if (lane < 16) attn[(size_t)u * 16 + lane] = a;

    // ---- setup: per-(sample,tap) weight + offset, 2 pairs per lane ----
    int   off[2];
    float w[2];
#pragma unroll
    for (int t2 = 0; t2 < 2; ++t2) {
        const int p  = lane + (t2 << 5);   // pair id 0..63
        const int j  = p >> 2;             // sample 0..15 (l = j>>2, pt = j&3)
        const int dx = p & 1;
        const int dy = (p >> 1) & 1;
        const int l  = j >> 2;
        const int Wl = 128 >> l;
        const int st = (int)((0x15141000u >> (l << 3)) & 0xFFu) << 10;  // level starts
        const float aw = __shfl(a, j, 32);
        const float xr = __shfl(myloc, 2 * j, 32);
        const float yr = __shfl(myloc, 2 * j + 1, 32);
        const float x = xr * (float)Wl - 0.5f;
        const float y = yr * (float)Wl - 0.5f;
        const float x0f = floorf(x), y0f = floorf(y);
        const float fx = x - x0f, fy = y - y0f;
        const int xi = (int)x0f + dx;
        const int yi = (int)y0f + dy;
        const float wx = dx ? fx : 1.f - fx;
        const float wy = dy ? fy : 1.f - fy;
        const bool valid = (xi >= 0) && (xi < Wl) && (yi >= 0) && (yi < Wl);
        w[t2] = valid ? wx * wy * aw : 0.f;
        const int cx = min(max(xi, 0), Wl - 1);
        const int cy = min(max(yi, 0), Wl - 1);
        off[t2] = st + cy * Wl + cx;
    }

    // ---- redistribute: all 8 (w,off) this lane consumes, hoisted shfls ----
    // lane consumes pair p = 8j + (lane>>2); owner lane = p&31, slot = p>>5
    float w8[8];
    int   off8[8];
#pragma unroll
    for (int j = 0; j < 8; ++j) {
        const int src = ((j & 3) << 3) + (lane >> 2);
        w8[j]   = __shfl(w[j >> 2], src, 32);
        off8[j] = __shfl(off[j >> 2], src, 32);
    }

    // ---- issue all 8 gathers (16B each), then FMA ----
    const _Float16* vb = value + (size_t)b * NK_ * D_ + h * HD_ + ((lane & 3) << 3);
    f16x8 vv[8];
#pragma unroll
    for (int j = 0; j < 8; ++j)
        vv[j] = *(const f16x8*)(vb + (size_t)off8[j] * 256);

    float acc[8] = {0.f, 0.f, 0.f, 0.f, 0.f, 0.f, 0.f, 0.f};
#pragma unroll
    for (int j = 0; j < 8; ++j)
#pragma unroll
        for (int c = 0; c < 8; ++c) acc[c] += w8[j] * (float)vv[j][c];

    // reduce over the 8 lanes sharing chan-group (lane&3): xor 4, 8, 16
#pragma unroll
    for (int mk = 4; mk <= 16; mk <<= 1)
#pragma unroll
        for (int c = 0; c < 8; ++c) acc[c] += __shfl_xor(acc[c], mk, 32);

    if (lane < 4) {
        f16x8 o;
#pragma unroll
        for (int c = 0; c < 8; ++c) o[c] = (_Float16)acc[c];
        *(f16x8*)&core[(size_t)bq * 256 + h * 32 + (lane << 3)] = o;
    }
}

// ---------------------------------------------------------------------------
extern "C" void kernel_launch(void* const* d_in, const int* in_sizes, int n_in,
                              void* d_out, int out_size, void* d_ws, size_t ws_size,
                              hipStream_t stream) {
    const float* query = (const float*)d_in[0];
    const float* rp    = (const float*)d_in[1];
    const float* flat  = (const float*)d_in[2];
    const float* Wv    = (const float*)d_in[5];
    const float* bv    = (const float*)d_in[6];
    const float* Woff  = (const float*)d_in[7];
    const float* boff  = (const float*)d_in[8];
    const float* Wattn = (const float*)d_in[9];
    const float* battn = (const float*)d_in[10];
    const float* Wout  = (const float*)d_in[11];
    const float* bout  = (const float*)d_in[12];

    float* out      = (float*)d_out;                 // (B,NQ,D)
    float* out_loc  = out + (size_t)M_ * D_;         // (B,NQ,NH,NL,NP,2)
    float* out_attn = out_loc + (size_t)M_ * D_;     // (B,NQ,NH,NL,NP)

    // ws: f16 weights + f16 activations
    _Float16* Bv_t    = (_Float16*)d_ws;             // [256][256]
    _Float16* Boff_t  = Bv_t + 65536;                // [256][256]
    _Float16* Battn_t = Boff_t + 65536;              // [128][256]
    _Float16* Bout_t  = Battn_t + 32768;             // [256][256]
    _Float16* flat16  = Bout_t + 65536;              // [M][256]
    _Float16* query16 = flat16 + (size_t)M_ * 256;   // [M][256]
    _Float16* value16 = query16 + (size_t)M_ * 256;  // [M][256]
    _Float16* core16  = value16 + (size_t)M_ * 256;  // [M][256]

    dim3 blk(256);
    // 0. weight prep (one launch)
    wconv_all<<<dim3(896), blk, 0, stream>>>(Wv, Woff, Wattn, Wout,
                                             Bv_t, Boff_t, Battn_t, Bout_t);
    // 0b. activation f16 conversion (flat + query fused into one launch)
    aconv2<<<dim3(2 * M_ * 64 / 256), blk, 0, stream>>>(flat, query, flat16, query16, M_ * 64);

    // 1. value16 = f16(flat @ Wv + bv)
    gemm_f16<256, 2><<<dim3(M_ / 128, 2), blk, 0, stream>>>(flat16, Bv_t, bv, value16, nullptr);
    // 2. loc = rp + (query @ Woff + boff)/norm  (direct to output)
    gemm_f16<256, 1><<<dim3(M_ / 128, 2), blk, 0, stream>>>(query16, Boff_t, boff, out_loc, rp);
    // 3. attn logits (direct to attn output; softmaxed in-place by deform_core)
    gemm_f16<128, 0><<<dim3(M_ / 128, 1), blk, 0, stream>>>(query16, Battn_t, battn, out_attn, nullptr);
    // 4. softmax + deformable sampling -> core16
    deform_core<<<dim3(M_ * NH_ / 8), blk, 0, stream>>>(value16, out_loc, out_attn, core16);
    // 5. out = core @ Wout + bout
    gemm_f16<256, 0><<<dim3(M_ / 128, 2), blk, 0, stream>>>(core16, Bout_t, bout, out, nullptr);
}

// Round 4
// 356.448 us; speedup vs baseline: 1.0509x; 1.0245x over previous
//
#include <hip/hip_runtime.h>
#include <cstdint>
#include <cstddef>

// Fixed problem constants (from reference setup)
#define B_    2
#define NQ_   21760
#define NK_   21760
#define D_    256
#define NH_   8
#define NL_   4
#define NP_   4
#define HD_   32
#define M_    (B_ * NQ_)   // 43520 = 340 * 128

typedef _Float16 f16x8 __attribute__((ext_vector_type(8)));
typedef _Float16 f16x4 __attribute__((ext_vector_type(4)));
typedef float    f32x4 __attribute__((ext_vector_type(4)));

// async global->LDS, 16B per lane; LDS dest = wave-uniform base + lane*16 [m97/m104]
__device__ __forceinline__ void lds16(const _Float16* g, _Float16* l) {
    __builtin_amdgcn_global_load_lds((const __attribute__((address_space(1))) void*)g,
                                     (__attribute__((address_space(3))) void*)l,
                                     16, 0, 0);
}

// ---------------------------------------------------------------------------
// Weight prep (all 4 in one launch): W[K][N] fp32 -> Bt[N][256] f16 transposed
// ---------------------------------------------------------------------------
__global__ __launch_bounds__(256) void wconv_all(const float* __restrict__ Wv,
                                                 const float* __restrict__ Woff,
                                                 const float* __restrict__ Wattn,
                                                 const float* __restrict__ Wout,
                                                 _Float16* __restrict__ Bv_t,
                                                 _Float16* __restrict__ Boff_t,
                                                 _Float16* __restrict__ Battn_t,
                                                 _Float16* __restrict__ Bout_t) {
    int id = blockIdx.x * 256 + threadIdx.x;
    if (id < 65536) {
        int k = id >> 8, n = id & 255;
        Bv_t[n * 256 + k] = (_Float16)Wv[k * 256 + n];
    } else if (id < 131072) {
        int e = id - 65536, k = e >> 8, n = e & 255;
        Boff_t[n * 256 + k] = (_Float16)Woff[k * 256 + n];
    } else if (id < 163840) {
        int e = id - 131072, k = e >> 7, n = e & 127;
        Battn_t[n * 256 + k] = (_Float16)Wattn[k * 128 + n];
    } else if (id < 229376) {
        int e = id - 163840, k = e >> 8, n = e & 255;
        Bout_t[n * 256 + k] = (_Float16)Wout[k * 256 + n];
    }
}

// ---------------------------------------------------------------------------
// fp32 -> f16 row conversion (one float4 -> one f16x4 per thread)
// Fused: converts flat (first n4each) then query (next n4each) in one launch.
// ---------------------------------------------------------------------------
__global__ __launch_bounds__(256) void aconv2(const float* __restrict__ X0,
                                              const float* __restrict__ X1,
                                              _Float16* __restrict__ Y0,
                                              _Float16* __restrict__ Y1, int n4each) {
    int id = blockIdx.x * 256 + threadIdx.x;
    const float* X;
    _Float16* Y;
    int e;
    if (id < n4each) { X = X0; Y = Y0; e = id; }
    else             { X = X1; Y = Y1; e = id - n4each; }
    float4 v = ((const float4*)X)[e];
    f16x4 o = {(_Float16)v.x, (_Float16)v.y, (_Float16)v.z, (_Float16)v.w};
    ((f16x4*)Y)[e] = o;
}

// ---------------------------------------------------------------------------
// f16 MFMA GEMM, m97-style: C[M,N] = A[M,256] @ Bt^T + bias
//   A: [M][256] f16 row-major; Bt: [N][256] f16 (pre-transposed weights)
// Tile 128x128, 256 thr = 4 waves (2x2), 4x4 frags 16x16x32, BK=32.
// Staging: global_load_lds width-16, XOR-swizzled 16B chunks:
//   LDS row r (32 f16 = 4 chunks); lds chunk q holds global chunk q ^ ((r>>1)&3)
//   -> fragment ds_read_b128 has max 2-way bank aliasing (free, m136).
// EPI: 0 = fp32 store, 1 = loc epilogue fp32,
//      2 = f16 store HEAD-MAJOR value layout [b][h][row][32]  (R3)
// ---------------------------------------------------------------------------
template <int N, int EPI>
__global__ __launch_bounds__(256) void gemm_f16(const _Float16* __restrict__ A,
                                                const _Float16* __restrict__ Bt,
                                                const float* __restrict__ bias,
                                                void* __restrict__ Cv,
                                                const float* __restrict__ rp) {
    constexpr int K = 256;
    constexpr int BK = 32;
    __shared__ _Float16 As[128 * 32];  // 8 KB
    __shared__ _Float16 Bs[128 * 32];  // 8 KB

    const int tid  = threadIdx.x;
    const int wave = tid >> 6;
    const int lane = tid & 63;
    const int m0 = blockIdx.x * 128;
    const int n0 = blockIdx.y * 128;
    const int wm = (wave & 1) << 6;
    const int wn = (wave >> 1) << 6;
    const int lm = lane & 15;
    const int quad = lane >> 4;

    // staging: wave stages rows [wave*32, wave*32+32) of As and Bs, 2 insts each
    // lane covers row srow (inst1) / srow+16 (inst2), lds chunk (lane&3),
    // which must hold global chunk g = (lane&3) ^ ((srow>>1)&3)  (same for +16)
    const int srow = (wave << 5) + (lane >> 2);
    const int g    = (lane & 3) ^ ((lane >> 3) & 3);
    const _Float16* Ag = A  + (size_t)(m0 + srow) * K + (g << 3);
    const _Float16* Bg = Bt + (size_t)(n0 + srow) * K + (g << 3);
    _Float16* AsW = &As[(wave << 5) * 32];
    _Float16* BsW = &Bs[(wave << 5) * 32];

    // fragment read: row = w*+i*16+lm, logical chunk = quad,
    // stored at lds chunk quad ^ ((lm>>1)&3)   [(row>>1)&3 == (lm>>1)&3]
    const int aswz = (quad ^ ((lm >> 1) & 3)) << 3;

    f32x4 acc[4][4];
#pragma unroll
    for (int i = 0; i < 4; ++i)
#pragma unroll
        for (int j = 0; j < 4; ++j) acc[i][j] = (f32x4){0.f, 0.f, 0.f, 0.f};

    for (int k0 = 0; k0 < K; k0 += BK) {
        if (k0) __syncthreads();  // prev iteration's ds_reads done before overwrite
        lds16(Ag + k0,                 AsW);
        lds16(Ag + (size_t)16 * K + k0, AsW + 16 * 32);
        lds16(Bg + k0,                 BsW);
        lds16(Bg + (size_t)16 * K + k0, BsW + 16 * 32);
        __syncthreads();          // drains vmcnt(0): tiles resident

        f16x8 af[4], bf[4];
#pragma unroll
        for (int i = 0; i < 4; ++i)
            af[i] = *(const f16x8*)&As[(wm + i * 16 + lm) * 32 + aswz];
#pragma unroll
        for (int j = 0; j < 4; ++j)
            bf[j] = *(const f16x8*)&Bs[(wn + j * 16 + lm) * 32 + aswz];
#pragma unroll
        for (int i = 0; i < 4; ++i)
#pragma unroll
            for (int j = 0; j < 4; ++j)
                acc[i][j] = __builtin_amdgcn_mfma_f32_16x16x32_f16(af[i], bf[j], acc[i][j], 0, 0, 0);
    }

    // epilogue: C/D layout col=lane&15, row=quad*4+reg  [m89/m91 verified]
    float bcol[4];
#pragma unroll
    for (int j = 0; j < 4; ++j) bcol[j] = bias[n0 + wn + j * 16 + lm];
#pragma unroll
    for (int i = 0; i < 4; ++i)
#pragma unroll
        for (int j = 0; j < 4; ++j) {
            const int col = n0 + wn + j * 16 + lm;
#pragma unroll
            for (int r = 0; r < 4; ++r) {
                const int row = m0 + wm + i * 16 + quad * 4 + r;
                float val = acc[i][j][r] + bcol[j];
                if (EPI == 1) {
                    const int c = col & 1;
                    const int l = (col >> 3) & 3;
                    const float inv = 1.f / (float)(128 >> l);
                    val = rp[(size_t)row * 8 + l * 2 + c] + val * inv;
                }
                if (EPI == 2) {
                    // head-major value: [b][h][r][32]; b=row/NQ_, h=col>>5, ch=col&31
                    const int bb = (row >= NQ_) ? 1 : 0;
                    const int rr = row - bb * NQ_;
                    const int hh = col >> 5;
                    const int ch = col & 31;
                    ((_Float16*)Cv)[((size_t)(bb * 8 + hh) * NQ_ + rr) * 32 + ch] = (_Float16)val;
                } else {
                    ((float*)Cv)[(size_t)row * N + col] = val;
                }
            }
        }
}

// ---------------------------------------------------------------------------
// Deformable sampling core, setup-hoisted, 16B-gather, XCD-PINNED head slices.
// R3: value is HEAD-MAJOR f16 [B][NH][NK][32]; one (b,h) slice = 1.36 MB,
// both batches of one head = 2.7 MB < 4 MB per-XCD L2.
// Block mapping: h = blockIdx.x & 7 (XCD = bid % 8 under round-robin dispatch,
// T1 mechanism) -> each XCD gathers only from its own 2.7 MB working set ->
// value gathers hit L2 instead of missing to Infinity Cache (R1/R2: FETCH
// pinned at 271 MB, 2.5 TB/s L2-fill = the bottleneck).
// One 32-lane unit per (b,q,h); block = 8 consecutive q of one (b,h).
// Setup: lane owns pairs p = lane, lane+32; weight+offset computed once.
// Main loop (r2 form, best measured): 8 iters, lane = pair-slot x chan-group,
// 2 shfl + one f16x8 (16B) gather + 8 FMA. Reduce xor 4/8/16.
// ---------------------------------------------------------------------------
__global__ __launch_bounds__(256) void deform_core(const _Float16* __restrict__ value,
                                                   const float* __restrict__ loc,
                                                   float* __restrict__ attn,
                                                   _Float16* __restrict__ core) {
    const int tid  = threadIdx.x;
    const int lane = tid & 31;
    const int h    = blockIdx.x & 7;        // == XCD id under round-robin dispatch
    const int i    = blockIdx.x >> 3;       // 0..5439
    const int b    = (i >= (NQ_ / 8)) ? 1 : 0;
    const int q    = (i - b * (NQ_ / 8)) * 8 + (tid >> 5);
    const int bq   = b * NQ_ + q;
    const int u    = (bq << 3) + h;         // original unit id for loc/attn

    const float myloc = loc[(size_t)u * 32 + lane];  // (l,p,c) 32 floats

    // softmax over 16 logits, in-place on attn output
    float lg = -1e30f;
    if (lane < 16) lg = attn[(size_t)u * 16 + lane];
    float m = lg;
#pragma unroll
    for (int mk = 8; mk; mk >>= 1) m = fmaxf(m, __shfl_xor(m, mk, 32));
    const float e = __expf(lg - m);
    float s = e;
#pragma unroll
    for (int mk = 8; mk; mk >>= 1) s += __shfl_xor(s, mk, 32);
    const float a = e / s;
    if (lane < 16) attn[(size_t)u * 16 + lane] = a;

    // ---- setup: per-(sample,tap) weight + offset, 2 pairs per lane ----
    int   off[2];
    float w[2];
#pragma unroll
    for (int t2 = 0; t2 < 2; ++t2) {
        const int p  = lane + (t2 << 5);   // pair id 0..63
        const int j  = p >> 2;             // sample 0..15 (l = j>>2, pt = j&3)
        const int dx = p & 1;
        const int dy = (p >> 1) & 1;
        const int l  = j >> 2;
        const int Wl = 128 >> l;
        const int st = (int)((0x15141000u >> (l << 3)) & 0xFFu) << 10;  // level starts
        const float aw = __shfl(a, j, 32);
        const float xr = __shfl(myloc, 2 * j, 32);
        const float yr = __shfl(myloc, 2 * j + 1, 32);
        const float x = xr * (float)Wl - 0.5f;
        const float y = yr * (float)Wl - 0.5f;
        const float x0f = floorf(x), y0f = floorf(y);
        const float fx = x - x0f, fy = y - y0f;
        const int xi = (int)x0f + dx;
        const int yi = (int)y0f + dy;
        const float wx = dx ? fx : 1.f - fx;
        const float wy = dy ? fy : 1.f - fy;
        const bool valid = (xi >= 0) && (xi < Wl) && (yi >= 0) && (yi < Wl);
        w[t2] = valid ? wx * wy * aw : 0.f;
        const int cx = min(max(xi, 0), Wl - 1);
        const int cy = min(max(yi, 0), Wl - 1);
        off[t2] = st + cy * Wl + cx;
    }

    // ---- main loop: iter j processes pairs j*8 + (lane>>2), 16B per lane ----
    // pair p = j*8 + (lane>>2); slot = j>>2; src lane = p & 31 = ((j&3)<<3)+(lane>>2)
    // head-major: row stride is 32 f16 (64 B)
    const _Float16* vb = value + (size_t)(b * 8 + h) * NQ_ * 32 + ((lane & 3) << 3);
    float acc[8] = {0.f, 0.f, 0.f, 0.f, 0.f, 0.f, 0.f, 0.f};
#pragma unroll
    for (int j = 0; j < 8; ++j) {
        const int src = ((j & 3) << 3) + (lane >> 2);
        const float ww = __shfl(w[j >> 2], src, 32);
        const int   oo = __shfl(off[j >> 2], src, 32);
        const f16x8 v = *(const f16x8*)(vb + (size_t)oo * 32);
#pragma unroll
        for (int c = 0; c < 8; ++c) acc[c] += ww * (float)v[c];
    }

    // reduce over the 8 lanes sharing chan-group (lane&3): xor 4, 8, 16
#pragma unroll
    for (int mk = 4; mk <= 16; mk <<= 1)
#pragma unroll
        for (int c = 0; c < 8; ++c) acc[c] += __shfl_xor(acc[c], mk, 32);

    if (lane < 4) {
        f16x8 o;
#pragma unroll
        for (int c = 0; c < 8; ++c) o[c] = (_Float16)acc[c];
        *(f16x8*)&core[(size_t)bq * 256 + h * 32 + (lane << 3)] = o;
    }
}

// ---------------------------------------------------------------------------
extern "C" void kernel_launch(void* const* d_in, const int* in_sizes, int n_in,
                              void* d_out, int out_size, void* d_ws, size_t ws_size,
                              hipStream_t stream) {
    const float* query = (const float*)d_in[0];
    const float* rp    = (const float*)d_in[1];
    const float* flat  = (const float*)d_in[2];
    const float* Wv    = (const float*)d_in[5];
    const float* bv    = (const float*)d_in[6];
    const float* Woff  = (const float*)d_in[7];
    const float* boff  = (const float*)d_in[8];
    const float* Wattn = (const float*)d_in[9];
    const float* battn = (const float*)d_in[10];
    const float* Wout  = (const float*)d_in[11];
    const float* bout  = (const float*)d_in[12];

    float* out      = (float*)d_out;                 // (B,NQ,D)
    float* out_loc  = out + (size_t)M_ * D_;         // (B,NQ,NH,NL,NP,2)
    float* out_attn = out_loc + (size_t)M_ * D_;     // (B,NQ,NH,NL,NP)

    // ws: f16 weights + f16 activations
    _Float16* Bv_t    = (_Float16*)d_ws;             // [256][256]
    _Float16* Boff_t  = Bv_t + 65536;                // [256][256]
    _Float16* Battn_t = Boff_t + 65536;              // [128][256]
    _Float16* Bout_t  = Battn_t + 32768;             // [256][256]
    _Float16* flat16  = Bout_t + 65536;              // [M][256]
    _Float16* query16 = flat16 + (size_t)M_ * 256;   // [M][256]
    _Float16* value16 = query16 + (size_t)M_ * 256;  // [B][NH][NK][32] head-major
    _Float16* core16  = value16 + (size_t)M_ * 256;  // [M][256]

    dim3 blk(256);
    // 0. weight prep (one launch)
    wconv_all<<<dim3(896), blk, 0, stream>>>(Wv, Woff, Wattn, Wout,
                                             Bv_t, Boff_t, Battn_t, Bout_t);
    // 0b. activation f16 conversion (flat + query fused into one launch)
    aconv2<<<dim3(2 * M_ * 64 / 256), blk, 0, stream>>>(flat, query, flat16, query16, M_ * 64);

    // 1. value16 = f16(flat @ Wv + bv), stored head-major [b][h][row][32]
    gemm_f16<256, 2><<<dim3(M_ / 128, 2), blk, 0, stream>>>(flat16, Bv_t, bv, value16, nullptr);
    // 2. loc = rp + (query @ Woff + boff)/norm  (direct to output)
    gemm_f16<256, 1><<<dim3(M_ / 128, 2), blk, 0, stream>>>(query16, Boff_t, boff, out_loc, rp);
    // 3. attn logits (direct to attn output; softmaxed in-place by deform_core)
    gemm_f16<128, 0><<<dim3(M_ / 128, 1), blk, 0, stream>>>(query16, Battn_t, battn, out_attn, nullptr);
    // 4. softmax + deformable sampling -> core16 (XCD-pinned head slices)
    deform_core<<<dim3(M_ * NH_ / 8), blk, 0, stream>>>(value16, out_loc, out_attn, core16);
    // 5. out = core @ Wout + bout
    gemm_f16<256, 0><<<dim3(M_ / 128, 2), blk, 0, stream>>>(core16, Bout_t, bout, out, nullptr);
}

// Round 5
// 344.874 us; speedup vs baseline: 1.0861x; 1.0336x over previous
//
#include <hip/hip_runtime.h>
#include <cstdint>
#include <cstddef>

// Fixed problem constants (from reference setup)
#define B_    2
#define NQ_   21760
#define NK_   21760
#define D_    256
#define NH_   8
#define NL_   4
#define NP_   4
#define HD_   32
#define M_    (B_ * NQ_)   // 43520 = 340 * 128

typedef _Float16 f16x8 __attribute__((ext_vector_type(8)));
typedef _Float16 f16x4 __attribute__((ext_vector_type(4)));
typedef float    f32x4 __attribute__((ext_vector_type(4)));

// async global->LDS, 16B per lane; LDS dest = wave-uniform base + lane*16 [m97/m104]
__device__ __forceinline__ void lds16(const _Float16* g, _Float16* l) {
    __builtin_amdgcn_global_load_lds((const __attribute__((address_space(1))) void*)g,
                                     (__attribute__((address_space(3))) void*)l,
                                     16, 0, 0);
}

// v_fma_mix_f32: acc(f32) += w(f16, HI half of pk) * v(f16, lo/hi half of vreg)
// op_sel_hi:[1,1,0] -> src0,src1 are f16; op_sel picks hi(1)/lo(0) half.
#define MIX_LO(acc, pk, vreg) \
    asm("v_fma_mix_f32 %0, %1, %2, %0 op_sel:[1,0,0] op_sel_hi:[1,1,0]" \
        : "+v"(acc) : "v"(pk), "v"(vreg))
#define MIX_HI(acc, pk, vreg) \
    asm("v_fma_mix_f32 %0, %1, %2, %0 op_sel:[1,1,0] op_sel_hi:[1,1,0]" \
        : "+v"(acc) : "v"(pk), "v"(vreg))

// ---------------------------------------------------------------------------
// Weight prep (all 4 in one launch): W[K][N] fp32 -> Bt[N][256] f16 transposed
// ---------------------------------------------------------------------------
__global__ __launch_bounds__(256) void wconv_all(const float* __restrict__ Wv,
                                                 const float* __restrict__ Woff,
                                                 const float* __restrict__ Wattn,
                                                 const float* __restrict__ Wout,
                                                 _Float16* __restrict__ Bv_t,
                                                 _Float16* __restrict__ Boff_t,
                                                 _Float16* __restrict__ Battn_t,
                                                 _Float16* __restrict__ Bout_t) {
    int id = blockIdx.x * 256 + threadIdx.x;
    if (id < 65536) {
        int k = id >> 8, n = id & 255;
        Bv_t[n * 256 + k] = (_Float16)Wv[k * 256 + n];
    } else if (id < 131072) {
        int e = id - 65536, k = e >> 8, n = e & 255;
        Boff_t[n * 256 + k] = (_Float16)Woff[k * 256 + n];
    } else if (id < 163840) {
        int e = id - 131072, k = e >> 7, n = e & 127;
        Battn_t[n * 256 + k] = (_Float16)Wattn[k * 128 + n];
    } else if (id < 229376) {
        int e = id - 163840, k = e >> 8, n = e & 255;
        Bout_t[n * 256 + k] = (_Float16)Wout[k * 256 + n];
    }
}

// ---------------------------------------------------------------------------
// fp32 -> f16 row conversion (one float4 -> one f16x4 per thread)
// Fused: converts flat (first n4each) then query (next n4each) in one launch.
// ---------------------------------------------------------------------------
__global__ __launch_bounds__(256) void aconv2(const float* __restrict__ X0,
                                              const float* __restrict__ X1,
                                              _Float16* __restrict__ Y0,
                                              _Float16* __restrict__ Y1, int n4each) {
    int id = blockIdx.x * 256 + threadIdx.x;
    const float* X;
    _Float16* Y;
    int e;
    if (id < n4each) { X = X0; Y = Y0; e = id; }
    else             { X = X1; Y = Y1; e = id - n4each; }
    float4 v = ((const float4*)X)[e];
    f16x4 o = {(_Float16)v.x, (_Float16)v.y, (_Float16)v.z, (_Float16)v.w};
    ((f16x4*)Y)[e] = o;
}

// ---------------------------------------------------------------------------
// f16 MFMA GEMM, m97-style: C[M,N] = A[M,256] @ Bt^T + bias
//   A: [M][256] f16 row-major; Bt: [N][256] f16 (pre-transposed weights)
// Tile 128x128, 256 thr = 4 waves (2x2), 4x4 frags 16x16x32, BK=32.
// Staging: global_load_lds width-16, XOR-swizzled 16B chunks:
//   LDS row r (32 f16 = 4 chunks); lds chunk q holds global chunk q ^ ((r>>1)&3)
//   -> fragment ds_read_b128 has max 2-way bank aliasing (free, m136).
// EPI: 0 = fp32 store, 1 = loc epilogue fp32,
//      2 = f16 store HEAD-MAJOR value layout [b][h][row][32]  (R3)
// ---------------------------------------------------------------------------
template <int N, int EPI>
__global__ __launch_bounds__(256) void gemm_f16(const _Float16* __restrict__ A,
                                                const _Float16* __restrict__ Bt,
                                                const float* __restrict__ bias,
                                                void* __restrict__ Cv,
                                                const float* __restrict__ rp) {
    constexpr int K = 256;
    constexpr int BK = 32;
    __shared__ _Float16 As[128 * 32];  // 8 KB
    __shared__ _Float16 Bs[128 * 32];  // 8 KB

    const int tid  = threadIdx.x;
    const int wave = tid >> 6;
    const int lane = tid & 63;
    const int m0 = blockIdx.x * 128;
    const int n0 = blockIdx.y * 128;
    const int wm = (wave & 1) << 6;
    const int wn = (wave >> 1) << 6;
    const int lm = lane & 15;
    const int quad = lane >> 4;

    // staging: wave stages rows [wave*32, wave*32+32) of As and Bs, 2 insts each
    // lane covers row srow (inst1) / srow+16 (inst2), lds chunk (lane&3),
    // which must hold global chunk g = (lane&3) ^ ((srow>>1)&3)  (same for +16)
    const int srow = (wave << 5) + (lane >> 2);
    const int g    = (lane & 3) ^ ((lane >> 3) & 3);
    const _Float16* Ag = A  + (size_t)(m0 + srow) * K + (g << 3);
    const _Float16* Bg = Bt + (size_t)(n0 + srow) * K + (g << 3);
    _Float16* AsW = &As[(wave << 5) * 32];
    _Float16* BsW = &Bs[(wave << 5) * 32];

    // fragment read: row = w*+i*16+lm, logical chunk = quad,
    // stored at lds chunk quad ^ ((lm>>1)&3)   [(row>>1)&3 == (lm>>1)&3]
    const int aswz = (quad ^ ((lm >> 1) & 3)) << 3;

    f32x4 acc[4][4];
#pragma unroll
    for (int i = 0; i < 4; ++i)
#pragma unroll
        for (int j = 0; j < 4; ++j) acc[i][j] = (f32x4){0.f, 0.f, 0.f, 0.f};

    for (int k0 = 0; k0 < K; k0 += BK) {
        if (k0) __syncthreads();  // prev iteration's ds_reads done before overwrite
        lds16(Ag + k0,                 AsW);
        lds16(Ag + (size_t)16 * K + k0, AsW + 16 * 32);
        lds16(Bg + k0,                 BsW);
        lds16(Bg + (size_t)16 * K + k0, BsW + 16 * 32);
        __syncthreads();          // drains vmcnt(0): tiles resident

        f16x8 af[4], bf[4];
#pragma unroll
        for (int i = 0; i < 4; ++i)
            af[i] = *(const f16x8*)&As[(wm + i * 16 + lm) * 32 + aswz];
#pragma unroll
        for (int j = 0; j < 4; ++j)
            bf[j] = *(const f16x8*)&Bs[(wn + j * 16 + lm) * 32 + aswz];
#pragma unroll
        for (int i = 0; i < 4; ++i)
#pragma unroll
            for (int j = 0; j < 4; ++j)
                acc[i][j] = __builtin_amdgcn_mfma_f32_16x16x32_f16(af[i], bf[j], acc[i][j], 0, 0, 0);
    }

    // epilogue: C/D layout col=lane&15, row=quad*4+reg  [m89/m91 verified]
    float bcol[4];
#pragma unroll
    for (int j = 0; j < 4; ++j) bcol[j] = bias[n0 + wn + j * 16 + lm];
#pragma unroll
    for (int i = 0; i < 4; ++i)
#pragma unroll
        for (int j = 0; j < 4; ++j) {
            const int col = n0 + wn + j * 16 + lm;
#pragma unroll
            for (int r = 0; r < 4; ++r) {
                const int row = m0 + wm + i * 16 + quad * 4 + r;
                float val = acc[i][j][r] + bcol[j];
                if (EPI == 1) {
                    const int c = col & 1;
                    const int l = (col >> 3) & 3;
                    const float inv = 1.f / (float)(128 >> l);
                    val = rp[(size_t)row * 8 + l * 2 + c] + val * inv;
                }
                if (EPI == 2) {
                    // head-major value: [b][h][r][32]; b=row/NQ_, h=col>>5, ch=col&31
                    const int bb = (row >= NQ_) ? 1 : 0;
                    const int rr = row - bb * NQ_;
                    const int hh = col >> 5;
                    const int ch = col & 31;
                    ((_Float16*)Cv)[((size_t)(bb * 8 + hh) * NQ_ + rr) * 32 + ch] = (_Float16)val;
                } else {
                    ((float*)Cv)[(size_t)row * N + col] = val;
                }
            }
        }
}

// ---------------------------------------------------------------------------
// Deformable sampling core, v5: XCD-pinned head slices + fma_mix inner loop.
// R4 post-mortem: duration pinned ~119us across r1-r4 while FETCH varied 5x
// and schedule varied -> VALU/issue-bound (VALUBusy ~79% at all occupancies).
// This round removes the two biggest instruction blocks in the main loop:
//   (a) 64x v_cvt_f32_f16 -> v_fma_mix_f32 inline asm (f16 consumed in-place)
//   (b) 2 shfl/iter -> 1: weight(f16) packed into hi16 of the row-offset int;
//       fma_mix reads w from the packed reg's HI half directly (no unpack).
// value is HEAD-MAJOR f16 [B][NH][NK][32]; (b,h) slice pair = 2.7 MB < 4 MB
// per-XCD L2; h = blockIdx.x & 7 pins each head's gathers to one XCD (R3:
// FETCH 271->54.6 MB verified).
// One 32-lane unit per (b,q,h); block = 8 consecutive q of one (b,h).
// ---------------------------------------------------------------------------
__global__ __launch_bounds__(256) void deform_core(const _Float16* __restrict__ value,
                                                   const float* __restrict__ loc,
                                                   float* __restrict__ attn,
                                                   _Float16* __restrict__ core) {
    const int tid  = threadIdx.x;
    const int lane = tid & 31;
    const int h    = blockIdx.x & 7;        // == XCD id under round-robin dispatch
    const int i    = blockIdx.x >> 3;       // 0..5439
    const int b    = (i >= (NQ_ / 8)) ? 1 : 0;
    const int q    = (i - b * (NQ_ / 8)) * 8 + (tid >> 5);
    const int bq   = b * NQ_ + q;
    const int u    = (bq << 3) + h;         // original unit id for loc/attn

    const float myloc = loc[(size_t)u * 32 + lane];  // (l,p,c) 32 floats

    // softmax over 16 logits, in-place on attn output
    float lg = -1e30f;
    if (lane < 16) lg = attn[(size_t)u * 16 + lane];
    float m = lg;
#pragma unroll
    for (int mk = 8; mk; mk >>= 1) m = fmaxf(m, __shfl_xor(m, mk, 32));
    const float e = __expf(lg - m);
    float s = e;
#pragma unroll
    for (int mk = 8; mk; mk >>= 1) s += __shfl_xor(s, mk, 32);
    const float a = e / s;
    if (lane < 16) attn[(size_t)u * 16 + lane] = a;

    // ---- setup: per-(sample,tap) packed {w(f16) hi16 | row-offset lo15} ----
    // total value rows = 21760 < 2^15, so offset fits 15 bits.
    int pk[2];
#pragma unroll
    for (int t2 = 0; t2 < 2; ++t2) {
        const int p  = lane + (t2 << 5);   // pair id 0..63
        const int j  = p >> 2;             // sample 0..15 (l = j>>2, pt = j&3)
        const int dx = p & 1;
        const int dy = (p >> 1) & 1;
        const int l  = j >> 2;
        const int Wl = 128 >> l;
        const int st = (int)((0x15141000u >> (l << 3)) & 0xFFu) << 10;  // level starts
        const float aw = __shfl(a, j, 32);
        const float xr = __shfl(myloc, 2 * j, 32);
        const float yr = __shfl(myloc, 2 * j + 1, 32);
        const float x = xr * (float)Wl - 0.5f;
        const float y = yr * (float)Wl - 0.5f;
        const float x0f = floorf(x), y0f = floorf(y);
        const float fx = x - x0f, fy = y - y0f;
        const int xi = (int)x0f + dx;
        const int yi = (int)y0f + dy;
        const float wx = dx ? fx : 1.f - fx;
        const float wy = dy ? fy : 1.f - fy;
        const bool valid = (xi >= 0) && (xi < Wl) && (yi >= 0) && (yi < Wl);
        const float wv = valid ? wx * wy * aw : 0.f;
        const int cx = min(max(xi, 0), Wl - 1);
        const int cy = min(max(yi, 0), Wl - 1);
        const int offr = st + cy * Wl + cx;
        const unsigned short wb =
            __builtin_bit_cast(unsigned short, (_Float16)wv);
        pk[t2] = ((int)wb << 16) | offr;
    }

    // ---- main loop: iter j processes pairs j*8 + (lane>>2), 16B per lane ----
    // pair p = j*8 + (lane>>2); slot = j>>2; src lane = p & 31 = ((j&3)<<3)+(lane>>2)
    // head-major: row stride is 32 f16 (64 B)
    const _Float16* vb = value + (size_t)(b * 8 + h) * NQ_ * 32 + ((lane & 3) << 3);
    float a0 = 0.f, a1 = 0.f, a2 = 0.f, a3 = 0.f;
    float a4 = 0.f, a5 = 0.f, a6 = 0.f, a7 = 0.f;
#pragma unroll
    for (int j = 0; j < 8; ++j) {
        const int src = ((j & 3) << 3) + (lane >> 2);
        const int pj  = __shfl(pk[j >> 2], src, 32);
        const uint4 v = *(const uint4*)(vb + (size_t)(pj & 0x7FFF) * 32);
        MIX_LO(a0, pj, v.x); MIX_HI(a1, pj, v.x);
        MIX_LO(a2, pj, v.y); MIX_HI(a3, pj, v.y);
        MIX_LO(a4, pj, v.z); MIX_HI(a5, pj, v.z);
        MIX_LO(a6, pj, v.w); MIX_HI(a7, pj, v.w);
    }

    // reduce over the 8 lanes sharing chan-group (lane&3): xor 4, 8, 16
#pragma unroll
    for (int mk = 4; mk <= 16; mk <<= 1) {
        a0 += __shfl_xor(a0, mk, 32);
        a1 += __shfl_xor(a1, mk, 32);
        a2 += __shfl_xor(a2, mk, 32);
        a3 += __shfl_xor(a3, mk, 32);
        a4 += __shfl_xor(a4, mk, 32);
        a5 += __shfl_xor(a5, mk, 32);
        a6 += __shfl_xor(a6, mk, 32);
        a7 += __shfl_xor(a7, mk, 32);
    }

    if (lane < 4) {
        f16x8 o = {(_Float16)a0, (_Float16)a1, (_Float16)a2, (_Float16)a3,
                   (_Float16)a4, (_Float16)a5, (_Float16)a6, (_Float16)a7};
        *(f16x8*)&core[(size_t)bq * 256 + h * 32 + (lane << 3)] = o;
    }
}

// ---------------------------------------------------------------------------
extern "C" void kernel_launch(void* const* d_in, const int* in_sizes, int n_in,
                              void* d_out, int out_size, void* d_ws, size_t ws_size,
                              hipStream_t stream) {
    const float* query = (const float*)d_in[0];
    const float* rp    = (const float*)d_in[1];
    const float* flat  = (const float*)d_in[2];
    const float* Wv    = (const float*)d_in[5];
    const float* bv    = (const float*)d_in[6];
    const float* Woff  = (const float*)d_in[7];
    const float* boff  = (const float*)d_in[8];
    const float* Wattn = (const float*)d_in[9];
    const float* battn = (const float*)d_in[10];
    const float* Wout  = (const float*)d_in[11];
    const float* bout  = (const float*)d_in[12];

    float* out      = (float*)d_out;                 // (B,NQ,D)
    float* out_loc  = out + (size_t)M_ * D_;         // (B,NQ,NH,NL,NP,2)
    float* out_attn = out_loc + (size_t)M_ * D_;     // (B,NQ,NH,NL,NP)

    // ws: f16 weights + f16 activations
    _Float16* Bv_t    = (_Float16*)d_ws;             // [256][256]
    _Float16* Boff_t  = Bv_t + 65536;                // [256][256]
    _Float16* Battn_t = Boff_t + 65536;              // [128][256]
    _Float16* Bout_t  = Battn_t + 32768;             // [256][256]
    _Float16* flat16  = Bout_t + 65536;              // [M][256]
    _Float16* query16 = flat16 + (size_t)M_ * 256;   // [M][256]
    _Float16* value16 = query16 + (size_t)M_ * 256;  // [B][NH][NK][32] head-major
    _Float16* core16  = value16 + (size_t)M_ * 256;  // [M][256]

    dim3 blk(256);
    // 0. weight prep (one launch)
    wconv_all<<<dim3(896), blk, 0, stream>>>(Wv, Woff, Wattn, Wout,
                                             Bv_t, Boff_t, Battn_t, Bout_t);
    // 0b. activation f16 conversion (flat + query fused into one launch)
    aconv2<<<dim3(2 * M_ * 64 / 256), blk, 0, stream>>>(flat, query, flat16, query16, M_ * 64);

    // 1. value16 = f16(flat @ Wv + bv), stored head-major [b][h][row][32]
    gemm_f16<256, 2><<<dim3(M_ / 128, 2), blk, 0, stream>>>(flat16, Bv_t, bv, value16, nullptr);
    // 2. loc = rp + (query @ Woff + boff)/norm  (direct to output)
    gemm_f16<256, 1><<<dim3(M_ / 128, 2), blk, 0, stream>>>(query16, Boff_t, boff, out_loc, rp);
    // 3. attn logits (direct to attn output; softmaxed in-place by deform_core)
    gemm_f16<128, 0><<<dim3(M_ / 128, 1), blk, 0, stream>>>(query16, Battn_t, battn, out_attn, nullptr);
    // 4. softmax + deformable sampling -> core16 (XCD-pinned head slices)
    deform_core<<<dim3(M_ * NH_ / 8), blk, 0, stream>>>(value16, out_loc, out_attn, core16);
    // 5. out = core @ Wout + bout
    gemm_f16<256, 0><<<dim3(M_ / 128, 2), blk, 0, stream>>>(core16, Bout_t, bout, out, nullptr);
}